// Round 8
// baseline (316.095 us; speedup 1.0000x reference)
//
#include <hip/hip_runtime.h>

namespace {
constexpr int ICH = 8, IH = 128, IW = 128;
constexpr int CPG = 4, PH = 31;
constexpr int ICS = 516;                 // per-ic LDS block: 4*128 + 4 pad
constexpr float EPS = 1e-5f;
constexpr float MPX = 126.f * 126.f;
constexpr int TOTAL_OUT = 128 * 64 * PH * PH;

__device__ __forceinline__ void gll16(const void* g, void* l) {
  __builtin_amdgcn_global_load_lds((const __attribute__((address_space(1))) void*)g,
                                   (__attribute__((address_space(3))) void*)l, 16, 0, 0);
}

// Process staged row RR: T2 += tap-row2 (completes), T1 += tap-row1, T0 += tap-row0.
#define ROW(RR, T2, T1, T0)                                                    \
  {                                                                            \
    _Pragma("unroll") for (int i4 = 0; i4 < 4; ++i4) {                         \
      const float* rp = bp + (4 * p + i4) * ICS + (RR) * IW + 4 * j;           \
      float4 v4 = *reinterpret_cast<const float4*>(rp);                        \
      float2 v2 = *reinterpret_cast<const float2*>(rp + 4);                    \
      float in[6] = {v4.x, v4.y, v4.z, v4.w, v2.x, v2.y};                      \
      _Pragma("unroll") for (int dw = 0; dw < 3; ++dw) {                       \
        const float w0 = wf[i4 * 9 + dw];                                      \
        const float w1 = wf[i4 * 9 + 3 + dw];                                  \
        const float w2 = wf[i4 * 9 + 6 + dw];                                  \
        _Pragma("unroll") for (int q = 0; q < 4; ++q) {                        \
          T2[q] = fmaf(in[q + dw], w2, T2[q]);                                 \
          T1[q] = fmaf(in[q + dw], w1, T1[q]);                                 \
          T0[q] = fmaf(in[q + dw], w0, T0[q]);                                 \
        }                                                                      \
      }                                                                        \
    }                                                                          \
  }

// Combine ic-halves, accumulate stats (masked col tail), emit flipped extreme.
#define FIN(T, DOSTATS, RE)                                                    \
  {                                                                            \
    float f0 = T[0] + __shfl_xor(T[0], 32, 64);                                \
    float f1 = T[1] + __shfl_xor(T[1], 32, 64);                                \
    float f2 = T[2] + __shfl_xor(T[2], 32, 64);                                \
    float f3 = T[3] + __shfl_xor(T[3], 32, 64);                                \
    if (DOSTATS) {                                                             \
      s1 += f0 + f1 + m23 * (f2 + f3);                                         \
      float qa = fmaf(f0, f0, f1 * f1);                                        \
      float qb = fmaf(f2, f2, f3 * f3);                                        \
      s2 += qa + m23 * qb;                                                     \
    }                                                                          \
    RE = fmaxf(fmaxf(flip * f0, flip * f1), fmaxf(flip * f2, flip * f3));      \
  }

#define ZERO(T) { T[0] = 0.f; T[1] = 0.f; T[2] = 0.f; T[3] = 0.f; }

// One 4-row stage. Completes output rows 4S-2, 4S-1, 4S, 4S+1 (names X,Y,Z,X).
// Pool window S-1 extreme is stored RAW (flip-adjusted) straight to global.
#define STAGE(S, X, Y, Z, DOS01, DOWIN)                                        \
  {                                                                            \
    __syncthreads();                                                           \
    const int cur = (S) & 1;                                                   \
    if ((S) < 31) issue(4 * ((S) + 1), cur ^ 1);                               \
    const float* bp = &buf[cur][0][0];                                         \
    float re0, re1, re2, re3;                                                  \
    ROW(0, X, Y, Z) FIN(X, DOS01, re0) ZERO(X)                                 \
    ROW(1, Y, Z, X) FIN(Y, DOS01, re1) ZERO(Y)                                 \
    if (DOWIN) {                                                               \
      float wfin = fmaxf(wprev, fmaxf(re0, re1));                              \
      if (p == 0 && j < 31) outraw[((S) - 1) * PH + j] = flip * wfin;          \
    }                                                                          \
    ROW(2, Z, X, Y) FIN(Z, true, re2) ZERO(Z)                                  \
    ROW(3, X, Y, Z) FIN(X, true, re3) ZERO(X)                                  \
    wprev = fmaxf(re2, re3);                                                   \
  }

// min-waves 2 -> VGPR budget 256: fits ~120-reg demand with NO spills.
// (min >= 4 pinned the budget to 64 and spilled GBs to scratch in R2-R5.)
__global__ __launch_bounds__(256, 2) void conv_pool_raw(
    const float* __restrict__ x, const float* __restrict__ cw,
    const float* __restrict__ cb, const float* __restrict__ gnw,
    const float* __restrict__ sc, float* __restrict__ out,
    float* __restrict__ ws) {
  __shared__ float buf[2][ICH][ICS];     // 33024 B, linear (global_load_lds dest)
  __shared__ float red[8];               // LDS total ~33.1 KB -> 4 blocks/CU

  const int bid = blockIdx.x;
  const int xcd = bid & 7;               // image's 16 groups share one XCD L2
  const int kb = bid >> 3;
  const int n = xcd * 16 + (kb >> 4);
  const int g = kb & 15;
  const int t = threadIdx.x;
  const int c = t >> 6;                  // wave = output channel within group
  const int u = t & 63;
  const int p = u >> 5;                  // ic-half: 0 -> ic 0..3, 1 -> ic 4..7
  const int j = u & 31;                  // output cols 4j..4j+3
  const int gc = g * CPG + c;

  float wf[36];                          // this lane's 4 ics x 9 taps
  {
    const float4* wp = reinterpret_cast<const float4*>(cw + gc * 72 + p * 36);
#pragma unroll
    for (int q = 0; q < 9; ++q) {
      float4 v = wp[q];
      wf[4 * q + 0] = v.x; wf[4 * q + 1] = v.y;
      wf[4 * q + 2] = v.z; wf[4 * q + 3] = v.w;
    }
  }
  const float flip = ((gnw[gc] * sc[gc]) >= 0.f) ? 1.f : -1.f;
  const float m23 = (j < 31) ? 1.f : 0.f;   // lane 31: only cols 124,125 valid

  const float* xn = x + (size_t)n * ICH * IH * IW;
  float* outraw = out + ((size_t)n * 64 + gc) * (PH * PH);

  // Stage 4 input rows (all 8 ic) into buf[which]; 16 x 1KB wave-chunks, 4/wave.
  auto issue = [&](int br, int which) {
#pragma unroll
    for (int k = 0; k < 4; ++k) {
      const int m = c * 4 + k;
      const int ic = m >> 1;
      const int r2 = (m & 1) * 2;        // rows r2, r2+1 of the stage
      const float* gp = xn + (size_t)(ic * IH + br + r2) * IW + u * 4;
      gll16(gp, &buf[which][ic][r2 * IW]);
    }
  };

  issue(0, 0);

  float s1 = 0.f, s2 = 0.f, wprev = 0.f;
  float A0[4] = {0, 0, 0, 0}, A1[4] = {0, 0, 0, 0}, A2[4] = {0, 0, 0, 0};

  // Stage 0: completed rows -2,-1 are invalid (no stats, no window).
  STAGE(0, A0, A1, A2, false, false)
  // Stages 1..30 in 3-phase triplets (pending-name permutation has period 3).
  for (int s = 1; s <= 28; s += 3) {
    STAGE(s,     A1, A2, A0, true, true)
    STAGE(s + 1, A2, A0, A1, true, true)
    STAGE(s + 2, A0, A1, A2, true, true)
  }
  // Stage 31 (31 % 3 == 1 -> phase (A1,A2,A0)); finalizes window 30 + rows 124,125 stats.
  STAGE(31, A1, A2, A0, true, true)

  // ---- block reduction (each value counted twice across ic-halves -> 0.5x) ----
#pragma unroll
  for (int off = 32; off > 0; off >>= 1) {
    s1 += __shfl_down(s1, off, 64);
    s2 += __shfl_down(s2, off, 64);
  }
  const float bc = cb[gc];
  if (u == 0) {
    float t1 = 0.5f * s1, t2 = 0.5f * s2;       // true raw per-channel sums
    red[c * 2] = t1 + MPX * bc;                 // add bias analytically
    red[c * 2 + 1] = t2 + 2.f * bc * t1 + MPX * bc * bc;
  }
  __syncthreads();
  if (t == 0) {
    float S1 = red[0] + red[2] + red[4] + red[6];
    float S2 = red[1] + red[3] + red[5] + red[7];
    constexpr float invN = 1.f / (CPG * 126.f * 126.f);
    float mean = S1 * invN;
    float var = S2 * invN - mean * mean;
    int G = n * 16 + g;
    ws[G * 2] = mean;
    ws[G * 2 + 1] = rsqrtf(var + EPS);
  }
}

__global__ __launch_bounds__(256) void gn_affine_clamp(
    float* __restrict__ out, const float* __restrict__ ws,
    const float* __restrict__ gnw, const float* __restrict__ gnb,
    const float* __restrict__ sc, const float* __restrict__ cb) {
  int i = blockIdx.x * 256 + threadIdx.x;
  const int stride = gridDim.x * 256;
  for (; i < TOTAL_OUT; i += stride) {
    int c = (i / 961) & 63;              // 961 = 31*31
    int n = i / 61504;                   // 61504 = 64*961
    int G = n * 16 + (c >> 2);
    float mean = ws[G * 2], inv = ws[G * 2 + 1];
    float gw = gnw[c];
    float A = gw * inv * sc[c];
    float B = (gnb[c] - mean * inv * gw) * sc[c] + A * cb[c];
    float v = fmaf(A, out[i], B);        // out[i] holds the selected raw extreme
    out[i] = fminf(fmaxf(v, 0.f), 1.f);
  }
}
}  // namespace

extern "C" void kernel_launch(void* const* d_in, const int* in_sizes, int n_in,
                              void* d_out, int out_size, void* d_ws, size_t ws_size,
                              hipStream_t stream) {
  const float* x   = (const float*)d_in[0];
  const float* cw  = (const float*)d_in[1];
  const float* cb  = (const float*)d_in[2];
  const float* gnw = (const float*)d_in[3];
  const float* gnb = (const float*)d_in[4];
  const float* sc  = (const float*)d_in[5];
  float* out = (float*)d_out;
  float* ws  = (float*)d_ws;             // 2048 groups x {mean, inv} = 16 KB
  hipLaunchKernelGGL(conv_pool_raw, dim3(2048), dim3(256), 0, stream,
                     x, cw, cb, gnw, sc, out, ws);
  hipLaunchKernelGGL(gn_affine_clamp, dim3(2048), dim3(256), 0, stream,
                     out, ws, gnw, gnb, sc, cb);
}

// Round 12
// 104.501 us; speedup vs baseline: 3.0248x; 3.0248x over previous
//
#include <hip/hip_runtime.h>
#include <hip/hip_fp16.h>

namespace {
constexpr int ICH = 8, IH = 128, IW = 128;
constexpr int CPG = 4, PH = 31;
constexpr int ICS = 516;
constexpr float EPS = 1e-5f;
constexpr float MPX = 126.f * 126.f;
constexpr int TOTAL_OUT = 128 * 64 * PH * PH;
constexpr size_t XH_BYTES = (size_t)128 * 128 * 128 * 8 * 2;   // 32 MB f16 [n][r][c][ic]
constexpr size_t WS_NEED = XH_BYTES + (size_t)128 * 16 * 4 * 2 * 4;

typedef _Float16 v8h __attribute__((ext_vector_type(8)));
typedef float v4f __attribute__((ext_vector_type(4)));
typedef unsigned short u16;
typedef unsigned int u32;

__device__ __forceinline__ void gll16(const void* g, void* l) {
  __builtin_amdgcn_global_load_lds((const __attribute__((address_space(1))) void*)g,
                                   (__attribute__((address_space(3))) void*)l, 16, 0, 0);
}

__device__ __forceinline__ u32 pkh(float a, float b) {
  unsigned short lo = __half_as_ushort(__float2half_rn(a));
  unsigned short hi = __half_as_ushort(__float2half_rn(b));
  return (u32)lo | ((u32)hi << 16);
}

// ---------- prepass: x[n][ic][r][c] f32 -> xh[n][r][c][ic] f16 ----------
__global__ __launch_bounds__(256) void pack_f16x8(const float* __restrict__ x,
                                                  u16* __restrict__ xh) {
  int i = blockIdx.x * 256 + threadIdx.x;      // pixel id, grid covers exactly 2^21
  int n = i >> 14, rc = i & 16383;
  const float* bp = x + ((size_t)n << 17) + rc;
  uint4 o;
  o.x = pkh(bp[0],      bp[16384]);
  o.y = pkh(bp[32768],  bp[49152]);
  o.z = pkh(bp[65536],  bp[81920]);
  o.w = pkh(bp[98304],  bp[114688]);
  *reinterpret_cast<uint4*>(xh + (size_t)i * 8) = o;
}

// ---------- main: implicit-GEMM conv via mfma_f32_16x16x32_f16 ----------
// Block = (n, quarter). 4 waves x 16 oc. K = tap*8+ic (taps 0..8, pad 9..11).
// A: lane holds W[16w + (l&15)][k=(l>>4)*8+i];  B: X[r+dh][c0+(l&15)+dw][ic=i].
// C/D: col=l&15 (position), row=(l>>4)*4+q (oc) [verified m89].
__global__ __launch_bounds__(256, 2) void conv_mfma(
    const u16* __restrict__ xh, const float* __restrict__ cw,
    const float* __restrict__ cb, const float* __restrict__ gnw,
    const float* __restrict__ sc, float* __restrict__ out,
    float* __restrict__ wsp) {
  __shared__ __align__(16) u16 ring[12][1056];   // 12 rows x 132 px x 8 ic, 25344 B

  const int bid = blockIdx.x;
  const int n = bid >> 2, qq = bid & 3;
  const int out_lo = qq * 32;
  const int out_hi = (qq == 3) ? 125 : out_lo + 31;
  const int NST = (qq == 3) ? 8 : 9;
  const int t = threadIdx.x;
  const int w = t >> 6, l = t & 63;
  const int colB = l & 15, qt = l >> 4;

  // Zero the per-row pixel pad (px 128..131): clamped-tap lanes can read it.
  for (int idx = t; idx < 12 * 32; idx += 256)
    ring[idx >> 5][1024 + (idx & 31)] = 0;

  // A fragments (weights), zero-padded taps 9..11.
  v8h af[3];
#pragma unroll
  for (int kc = 0; kc < 3; ++kc) {
    const int tap = kc * 4 + qt;
    const int ocA = 16 * w + colB;
#pragma unroll
    for (int i = 0; i < 8; ++i)
      af[kc][i] = (tap < 9) ? (_Float16)cw[ocA * 72 + i * 9 + tap] : (_Float16)0.f;
  }
  // B per-lane address constants (tap clamped to 8 for pad lanes: A=0 there).
  int eofc[3], dhl[3];
#pragma unroll
  for (int kc = 0; kc < 3; ++kc) {
    int tap = kc * 4 + qt; tap = (tap > 8) ? 8 : tap;
    dhl[kc] = tap / 3;
    eofc[kc] = (colB + tap % 3) * 8;
  }
  float flip[4];
#pragma unroll
  for (int q = 0; q < 4; ++q) {
    int oc = 16 * w + qt * 4 + q;
    flip[q] = (gnw[oc] * sc[oc] >= 0.f) ? 1.f : -1.f;
  }
  const u16* rb = &ring[0][0];

  // Stage 4 input rows (2 KB each) into ring slots; wave w stages chunks 2w,2w+1.
  auto issue = [&](int s) {
#pragma unroll
    for (int k = 0; k < 2; ++k) {
      int mk = w * 2 + k;
      int grow = out_lo + 4 * s + (mk >> 1);
      int hv = mk & 1;
      int slot = grow % 12;
      gll16(xh + ((size_t)(n * 128 + grow) * 128 + hv * 64) * 8 + l * 8,
            (void*)&ring[slot][hv * 512]);
    }
  };

  issue(0);

  float s1q[4] = {0.f, 0.f, 0.f, 0.f};
  float s2g = 0.f;
  float pacc[8][4];
#pragma unroll
  for (int ci = 0; ci < 8; ++ci)
#pragma unroll
    for (int q = 0; q < 4; ++q) pacc[ci][q] = -3.4e38f;

  for (int s = 0; s < NST; ++s) {
    __syncthreads();                      // stage s landed; ring 12 keeps RAW safe
    if (s + 1 < NST) issue(s + 1);
#pragma unroll
    for (int ri = 0; ri < 4; ++ri) {
      const int r = out_lo + 4 * s - 2 + ri;
      if (r < out_lo || r > out_hi) continue;
      const int rm = r % 12;
      int eoff[3];
#pragma unroll
      for (int kc = 0; kc < 3; ++kc) {
        int sl = rm + dhl[kc];
        if (sl >= 12) sl -= 12;
        eoff[kc] = sl * 1056 + eofc[kc];
      }
#pragma unroll
      for (int ci = 0; ci < 8; ++ci) {
        v4f acc = {0.f, 0.f, 0.f, 0.f};
#pragma unroll
        for (int kc = 0; kc < 3; ++kc) {
          v8h bf = *reinterpret_cast<const v8h*>(rb + eoff[kc] + ci * 128);
          acc = __builtin_amdgcn_mfma_f32_16x16x32_f16(af[kc], bf, acc, 0, 0, 0);
        }
        if (ci < 7) {
#pragma unroll
          for (int q = 0; q < 4; ++q) {
            s1q[q] += acc[q];
            s2g = fmaf(acc[q], acc[q], s2g);
            pacc[ci][q] = fmaxf(pacc[ci][q], flip[q] * acc[q]);
          }
        } else {                           // cols 112..127: mask 126,127 (colB>=14)
          const bool va = (colB < 14);
#pragma unroll
          for (int q = 0; q < 4; ++q) {
            float a = va ? acc[q] : 0.f;
            s1q[q] += a;
            s2g = fmaf(a, a, s2g);         // a*a: masked lanes add exact 0
            float fv = va ? flip[q] * acc[q] : -3.4e38f;
            pacc[7][q] = fmaxf(pacc[7][q], fv);
          }
        }
      }
      if ((r & 3) == 3) {                  // flush pool window row pr = r>>2
        const int pr = r >> 2;
        float* ob = out + (((size_t)n * 64 + 16 * w + qt * 4) * PH + pr) * PH;
#pragma unroll
        for (int ci = 0; ci < 8; ++ci) {
#pragma unroll
          for (int q = 0; q < 4; ++q) {
            float pm = pacc[ci][q];
            pm = fmaxf(pm, __shfl_xor(pm, 1, 64));
            pm = fmaxf(pm, __shfl_xor(pm, 2, 64));
            if ((l & 3) == 0 && (ci < 7 || colB < 12)) {  // pc<=30 only
              int pc = ci * 4 + (colB >> 2);
              ob[(size_t)q * (PH * PH) + pc] = flip[q] * pm;   // raw extreme
            }
            pacc[ci][q] = -3.4e38f;
          }
        }
      }
    }
  }

  // per-quarter stats reduce (16 lanes); fold bias with the QUARTER's count
  // (R11 BUG: used full-image MPX here -> bias counted 4x across quarters).
#pragma unroll
  for (int off = 1; off <= 8; off <<= 1) {
#pragma unroll
    for (int q = 0; q < 4; ++q) s1q[q] += __shfl_xor(s1q[q], off, 64);
    s2g += __shfl_xor(s2g, off, 64);
  }
  if ((l & 15) == 0) {
    const float cntq = 126.f * (float)(out_hi - out_lo + 1);   // 32 or 30 rows
    float S1 = 0.f, S2 = s2g;
#pragma unroll
    for (int q = 0; q < 4; ++q) {
      float b = cb[16 * w + qt * 4 + q];
      S1 += s1q[q] + cntq * b;
      S2 += 2.f * b * s1q[q] + cntq * b * b;
    }
    int g = 4 * w + qt;
    float* wp = wsp + ((size_t)(n * 16 + g) * 4 + qq) * 2;
    wp[0] = S1; wp[1] = S2;
  }
}

// ---------- epilogue kernel: GN affine + clamp over raw pool extremes ----------
__global__ __launch_bounds__(256) void gn_affine_clamp(
    float* __restrict__ out, const float* __restrict__ wsp,
    const float* __restrict__ gnw, const float* __restrict__ gnb,
    const float* __restrict__ sc, const float* __restrict__ cb) {
  int i = blockIdx.x * 256 + threadIdx.x;
  const int stride = gridDim.x * 256;
  for (; i < TOTAL_OUT; i += stride) {
    int c = (i / 961) & 63;
    int n = i / 61504;
    const float* wp = wsp + ((size_t)(n * 16 + (c >> 2)) * 4) * 2;
    float S1 = wp[0] + wp[2] + wp[4] + wp[6];
    float S2 = wp[1] + wp[3] + wp[5] + wp[7];
    constexpr float invN = 1.f / (4.f * MPX);
    float mean = S1 * invN;
    float var = S2 * invN - mean * mean;
    float inv = rsqrtf(var + EPS);
    float gw = gnw[c];
    float A = gw * inv * sc[c];
    float B = (gnb[c] - mean * inv * gw) * sc[c] + A * cb[c];
    float v = fmaf(A, out[i], B);
    out[i] = fminf(fmaxf(v, 0.f), 1.f);
  }
}

// ---------- f32 fallback (verbatim R6 winner, used only if ws too small) ----------
#define FIN(T, DOSTATS, RE)                                                    \
  {                                                                            \
    float f0 = T[0] + __shfl_xor(T[0], 32, 64);                                \
    float f1 = T[1] + __shfl_xor(T[1], 32, 64);                                \
    float f2 = T[2] + __shfl_xor(T[2], 32, 64);                                \
    float f3 = T[3] + __shfl_xor(T[3], 32, 64);                                \
    if (DOSTATS) {                                                             \
      s1 += f0 + f1 + m23 * (f2 + f3);                                         \
      float qa = fmaf(f0, f0, f1 * f1);                                        \
      float qb = fmaf(f2, f2, f3 * f3);                                        \
      s2 += qa + m23 * qb;                                                     \
    }                                                                          \
    RE = fmaxf(fmaxf(flip * f0, flip * f1), fmaxf(flip * f2, flip * f3));      \
  }
#define ZERO(T) { T[0] = 0.f; T[1] = 0.f; T[2] = 0.f; T[3] = 0.f; }
#define ROWF(RR, T2, T1, T0)                                                   \
  {                                                                            \
    _Pragma("unroll") for (int i4 = 0; i4 < 4; ++i4) {                         \
      const float* rp = bp + (4 * p + i4) * ICS + (RR) * IW + 4 * j;           \
      float4 v4 = *reinterpret_cast<const float4*>(rp);                        \
      float2 v2 = *reinterpret_cast<const float2*>(rp + 4);                    \
      float in[6] = {v4.x, v4.y, v4.z, v4.w, v2.x, v2.y};                      \
      _Pragma("unroll") for (int dw = 0; dw < 3; ++dw) {                       \
        const float w0 = wf[i4 * 9 + dw];                                      \
        const float w1 = wf[i4 * 9 + 3 + dw];                                  \
        const float w2 = wf[i4 * 9 + 6 + dw];                                  \
        _Pragma("unroll") for (int q = 0; q < 4; ++q) {                        \
          T2[q] = fmaf(in[q + dw], w2, T2[q]);                                 \
          T1[q] = fmaf(in[q + dw], w1, T1[q]);                                 \
          T0[q] = fmaf(in[q + dw], w0, T0[q]);                                 \
        }                                                                      \
      }                                                                        \
    }                                                                          \
  }
#define STAGEF(S, X, Y, Z, DOS01, DOWIN)                                       \
  {                                                                            \
    __syncthreads();                                                           \
    const int cur = (S) & 1;                                                   \
    if ((S) < 31) issue(4 * ((S) + 1), cur ^ 1);                               \
    const float* bp = &buf[cur][0][0];                                         \
    float re0, re1, re2, re3;                                                  \
    ROWF(0, X, Y, Z) FIN(X, DOS01, re0) ZERO(X)                                \
    ROWF(1, Y, Z, X) FIN(Y, DOS01, re1) ZERO(Y)                                \
    if (DOWIN) {                                                               \
      float wfin = fmaxf(wprev, fmaxf(re0, re1));                              \
      if (p == 0 && j < 31) mm[c][(S) - 1][j] = __float2half(flip * wfin);     \
    }                                                                          \
    ROWF(2, Z, X, Y) FIN(Z, true, re2) ZERO(Z)                                 \
    ROWF(3, X, Y, Z) FIN(X, true, re3) ZERO(X)                                 \
    wprev = fmaxf(re2, re3);                                                   \
  }

__global__ __launch_bounds__(256, 2) void fused_conv_gn_pool_f32(
    const float* __restrict__ x, const float* __restrict__ cw,
    const float* __restrict__ cb, const float* __restrict__ gnw,
    const float* __restrict__ gnb, const float* __restrict__ sc,
    float* __restrict__ out) {
  __shared__ float buf[2][ICH][ICS];
  __shared__ __half mm[CPG][PH][PH];
  __shared__ float red[8];
  __shared__ float stats[2];

  const int bid = blockIdx.x;
  const int xcd = bid & 7;
  const int kb = bid >> 3;
  const int n = xcd * 16 + (kb >> 4);
  const int g = kb & 15;
  const int t = threadIdx.x;
  const int c = t >> 6;
  const int u = t & 63;
  const int p = u >> 5;
  const int j = u & 31;
  const int gc = g * CPG + c;

  float wf[36];
  {
    const float4* wp = reinterpret_cast<const float4*>(cw + gc * 72 + p * 36);
#pragma unroll
    for (int q = 0; q < 9; ++q) {
      float4 v = wp[q];
      wf[4 * q + 0] = v.x; wf[4 * q + 1] = v.y;
      wf[4 * q + 2] = v.z; wf[4 * q + 3] = v.w;
    }
  }
  const float flip = ((gnw[gc] * sc[gc]) >= 0.f) ? 1.f : -1.f;
  const float m23 = (j < 31) ? 1.f : 0.f;

  const float* xn = x + (size_t)n * ICH * IH * IW;

  auto issue = [&](int br, int which) {
#pragma unroll
    for (int k = 0; k < 4; ++k) {
      const int m = c * 4 + k;
      const int ic = m >> 1;
      const int r2 = (m & 1) * 2;
      const float* gp = xn + (size_t)(ic * IH + br + r2) * IW + u * 4;
      gll16(gp, &buf[which][ic][r2 * IW]);
    }
  };

  issue(0, 0);

  float s1 = 0.f, s2 = 0.f, wprev = 0.f;
  float A0[4] = {0, 0, 0, 0}, A1[4] = {0, 0, 0, 0}, A2[4] = {0, 0, 0, 0};

  STAGEF(0, A0, A1, A2, false, false)
  for (int s = 1; s <= 28; s += 3) {
    STAGEF(s,     A1, A2, A0, true, true)
    STAGEF(s + 1, A2, A0, A1, true, true)
    STAGEF(s + 2, A0, A1, A2, true, true)
  }
  STAGEF(31, A1, A2, A0, true, true)

#pragma unroll
  for (int off = 32; off > 0; off >>= 1) {
    s1 += __shfl_down(s1, off, 64);
    s2 += __shfl_down(s2, off, 64);
  }
  const float bc = cb[gc];
  if (u == 0) {
    float t1 = 0.5f * s1, t2 = 0.5f * s2;
    red[c * 2] = t1 + MPX * bc;
    red[c * 2 + 1] = t2 + 2.f * bc * t1 + MPX * bc * bc;
  }
  __syncthreads();
  if (t == 0) {
    float S1 = red[0] + red[2] + red[4] + red[6];
    float S2 = red[1] + red[3] + red[5] + red[7];
    constexpr float invN = 1.f / (CPG * 126.f * 126.f);
    float mean = S1 * invN;
    float var = S2 * invN - mean * mean;
    stats[0] = mean;
    stats[1] = rsqrtf(var + EPS);
  }
  __syncthreads();
  const float mean = stats[0], inv = stats[1];

  float* outp = out + ((size_t)n * 64 + g * CPG) * (PH * PH);
  for (int kk = 0; kk < 16; ++kk) {
    int idx = t + kk * 256;
    if (idx < CPG * PH * PH) {
      int cc = idx / (PH * PH);
      int rem = idx - cc * (PH * PH);
      float e = __half2float(mm[cc][rem / PH][rem % PH]);
      int gcc = g * CPG + cc;
      float gw = gnw[gcc];
      float A = gw * inv * sc[gcc];
      float B = (gnb[gcc] - mean * inv * gw) * sc[gcc] + A * cb[gcc];
      float v = fmaf(A, e, B);
      v = fminf(fmaxf(v, 0.f), 1.f);
      outp[cc * (PH * PH) + rem] = v;
    }
  }
}
}  // namespace

extern "C" void kernel_launch(void* const* d_in, const int* in_sizes, int n_in,
                              void* d_out, int out_size, void* d_ws, size_t ws_size,
                              hipStream_t stream) {
  const float* x   = (const float*)d_in[0];
  const float* cw  = (const float*)d_in[1];
  const float* cb  = (const float*)d_in[2];
  const float* gnw = (const float*)d_in[3];
  const float* gnb = (const float*)d_in[4];
  const float* sc  = (const float*)d_in[5];
  float* out = (float*)d_out;

  if (ws_size >= WS_NEED) {
    u16* xh = (u16*)d_ws;
    float* wsp = (float*)((char*)d_ws + XH_BYTES);
    hipLaunchKernelGGL(pack_f16x8, dim3(8192), dim3(256), 0, stream, x, xh);
    hipLaunchKernelGGL(conv_mfma, dim3(512), dim3(256), 0, stream,
                       xh, cw, cb, gnw, sc, out, wsp);
    hipLaunchKernelGGL(gn_affine_clamp, dim3(2048), dim3(256), 0, stream,
                       out, wsp, gnw, gnb, sc, cb);
  } else {
    hipLaunchKernelGGL(fused_conv_gn_pool_f32, dim3(2048), dim3(256), 0, stream,
                       x, cw, cb, gnw, gnb, sc, out);
  }
}

// Round 13
// 99.328 us; speedup vs baseline: 3.1823x; 1.0521x over previous
//
#include <hip/hip_runtime.h>
#include <hip/hip_fp16.h>

namespace {
constexpr int ICH = 8, IH = 128, IW = 128;
constexpr int CPG = 4, PH = 31;
constexpr int ICS = 516;
constexpr float EPS = 1e-5f;
constexpr float MPX = 126.f * 126.f;
constexpr int TOTAL_OUT = 128 * 64 * PH * PH;
constexpr size_t XH_BYTES = (size_t)128 * 128 * 128 * 8 * 2;   // 32 MB f16 [n][r][c][ic]
constexpr size_t WS_NEED = XH_BYTES + (size_t)128 * 16 * 8 * 2 * 4;

typedef _Float16 v8h __attribute__((ext_vector_type(8)));
typedef float v4f __attribute__((ext_vector_type(4)));
typedef unsigned short u16;
typedef unsigned int u32;

__device__ __forceinline__ void gll16(const void* g, void* l) {
  __builtin_amdgcn_global_load_lds((const __attribute__((address_space(1))) void*)g,
                                   (__attribute__((address_space(3))) void*)l, 16, 0, 0);
}

__device__ __forceinline__ u32 pkh(float a, float b) {
  unsigned short lo = __half_as_ushort(__float2half_rn(a));
  unsigned short hi = __half_as_ushort(__float2half_rn(b));
  return (u32)lo | ((u32)hi << 16);
}

// ---------- prepass: x[n][ic][r][c] f32 -> xh[n][r][c][ic] f16 ----------
__global__ __launch_bounds__(256) void pack_f16x8(const float* __restrict__ x,
                                                  u16* __restrict__ xh) {
  int i = blockIdx.x * 256 + threadIdx.x;      // pixel id, grid covers exactly 2^21
  int n = i >> 14, rc = i & 16383;
  const float* bp = x + ((size_t)n << 17) + rc;
  uint4 o;
  o.x = pkh(bp[0],      bp[16384]);
  o.y = pkh(bp[32768],  bp[49152]);
  o.z = pkh(bp[65536],  bp[81920]);
  o.w = pkh(bp[98304],  bp[114688]);
  *reinterpret_cast<uint4*>(xh + (size_t)i * 8) = o;
}

// ---------- main: implicit-GEMM conv via mfma_f32_16x16x32_f16 ----------
// Block = (n, eighth e). 4 waves x 16 oc. K = tap*8+ic (taps 0..8, pad 9..11).
// A: lane holds W[16w + (l&15)][k=(l>>4)*8+i], pre-multiplied by flip(oc);
// B: X[r+dh][c0+(l&15)+dw][ic=i].  C/D: col=l&15, row=(l>>4)*4+q [m89].
__global__ __launch_bounds__(256, 2) void conv_mfma(
    const u16* __restrict__ xh, const float* __restrict__ cw,
    const float* __restrict__ cb, const float* __restrict__ gnw,
    const float* __restrict__ sc, float* __restrict__ out,
    float* __restrict__ wsp) {
  __shared__ __align__(16) u16 ring[12][1056];   // 12 rows x 132 px x 8 ic, 25344 B

  const int bid = blockIdx.x;
  const int n = bid >> 3, e = bid & 7;
  const int out_lo = e * 16;
  const int out_hi = (e == 7) ? 125 : out_lo + 15;
  const int NST = (e == 7) ? 4 : 5;              // e=7 stages rows 112..127 exactly
  const int t = threadIdx.x;
  const int w = t >> 6, l = t & 63;
  const int colB = l & 15, qt = l >> 4;

  // Zero the per-row pixel pad (px 128..131): clamped-tap lanes can read it.
  for (int idx = t; idx < 12 * 32; idx += 256)
    ring[idx >> 5][1024 + (idx & 31)] = 0;

  // A fragments (weights), zero-padded taps 9..11, flip folded in (sign of
  // gnw*sc for this A-row's oc): pool-max then needs NO per-element multiply.
  const int ocA = 16 * w + colB;
  const float flipA = (gnw[ocA] * sc[ocA] >= 0.f) ? 1.f : -1.f;
  v8h af[3];
#pragma unroll
  for (int kc = 0; kc < 3; ++kc) {
    const int tap = kc * 4 + qt;
#pragma unroll
    for (int i = 0; i < 8; ++i)
      af[kc][i] = (tap < 9) ? (_Float16)(flipA * cw[ocA * 72 + i * 9 + tap])
                            : (_Float16)0.f;
  }
  // B per-lane address constants (tap clamped to 8 for pad lanes: A=0 there).
  int eofc[3], dhl[3];
#pragma unroll
  for (int kc = 0; kc < 3; ++kc) {
    int tap = kc * 4 + qt; tap = (tap > 8) ? 8 : tap;
    dhl[kc] = tap / 3;
    eofc[kc] = (colB + tap % 3) * 8;
  }
  float flip[4];
#pragma unroll
  for (int q = 0; q < 4; ++q) {
    int oc = 16 * w + qt * 4 + q;
    flip[q] = (gnw[oc] * sc[oc] >= 0.f) ? 1.f : -1.f;
  }
  const u16* rb = &ring[0][0];

  // Stage 4 input rows (2 KB each) into ring slots; wave w stages chunks 2w,2w+1.
  auto issue = [&](int s) {
#pragma unroll
    for (int k = 0; k < 2; ++k) {
      int mk = w * 2 + k;
      int grow = out_lo + 4 * s + (mk >> 1);
      int hv = mk & 1;
      int slot = grow % 12;
      gll16(xh + ((size_t)(n * 128 + grow) * 128 + hv * 64) * 8 + l * 8,
            (void*)&ring[slot][hv * 512]);
    }
  };

  issue(0);

  float s1q[4] = {0.f, 0.f, 0.f, 0.f};
  float s2g = 0.f;
  float pacc[8][4];
#pragma unroll
  for (int ci = 0; ci < 8; ++ci)
#pragma unroll
    for (int q = 0; q < 4; ++q) pacc[ci][q] = -3.4e38f;

  for (int s = 0; s < NST; ++s) {
    __syncthreads();                      // stage s landed; ring 12 keeps RAW safe
    if (s + 1 < NST) issue(s + 1);
#pragma unroll
    for (int ri = 0; ri < 4; ++ri) {
      const int r = out_lo + 4 * s - 2 + ri;
      if (r < out_lo || r > out_hi) continue;
      const int rm = r % 12;
      int eoff[3];
#pragma unroll
      for (int kc = 0; kc < 3; ++kc) {
        int sl = rm + dhl[kc];
        if (sl >= 12) sl -= 12;
        eoff[kc] = sl * 1056 + eofc[kc];
      }
#pragma unroll
      for (int ci = 0; ci < 8; ++ci) {
        v4f acc = {0.f, 0.f, 0.f, 0.f};   // holds flip(oc)*conv (no bias)
#pragma unroll
        for (int kc = 0; kc < 3; ++kc) {
          v8h bf = *reinterpret_cast<const v8h*>(rb + eoff[kc] + ci * 128);
          acc = __builtin_amdgcn_mfma_f32_16x16x32_f16(af[kc], bf, acc, 0, 0, 0);
        }
        if (ci < 7) {
#pragma unroll
          for (int q = 0; q < 4; ++q) {
            s1q[q] += acc[q];
            s2g = fmaf(acc[q], acc[q], s2g);
            pacc[ci][q] = fmaxf(pacc[ci][q], acc[q]);
          }
        } else {                           // cols 112..127: mask 126,127 (colB>=14)
          const bool va = (colB < 14);
#pragma unroll
          for (int q = 0; q < 4; ++q) {
            float a = va ? acc[q] : 0.f;
            s1q[q] += a;
            s2g = fmaf(a, a, s2g);
            float fv = va ? acc[q] : -3.4e38f;
            pacc[7][q] = fmaxf(pacc[7][q], fv);
          }
        }
      }
      if ((r & 3) == 3) {                  // flush pool window row pr = r>>2
        const int pr = r >> 2;
        float* ob = out + (((size_t)n * 64 + 16 * w + qt * 4) * PH + pr) * PH;
#pragma unroll
        for (int ci = 0; ci < 8; ++ci) {
#pragma unroll
          for (int q = 0; q < 4; ++q) {
            float pm = pacc[ci][q];
            pm = fmaxf(pm, __shfl_xor(pm, 1, 64));
            pm = fmaxf(pm, __shfl_xor(pm, 2, 64));
            if ((l & 3) == 0 && (ci < 7 || colB < 12)) {  // pc<=30 only
              int pc = ci * 4 + (colB >> 2);
              ob[(size_t)q * (PH * PH) + pc] = flip[q] * pm;   // raw extreme
            }
            pacc[ci][q] = -3.4e38f;
          }
        }
      }
    }
  }

  // per-eighth stats reduce (16 lanes); un-flip s1; fold bias with eighth count.
#pragma unroll
  for (int off = 1; off <= 8; off <<= 1) {
#pragma unroll
    for (int q = 0; q < 4; ++q) s1q[q] += __shfl_xor(s1q[q], off, 64);
    s2g += __shfl_xor(s2g, off, 64);
  }
  if ((l & 15) == 0) {
    const float cnte = 126.f * (float)(out_hi - out_lo + 1);   // 16 or 14 rows
    float S1 = 0.f, S2 = s2g;
#pragma unroll
    for (int q = 0; q < 4; ++q) {
      float s1t = flip[q] * s1q[q];        // undo folded flip for the mean
      float b = cb[16 * w + qt * 4 + q];
      S1 += s1t + cnte * b;
      S2 += 2.f * b * s1t + cnte * b * b;
    }
    int g = 4 * w + qt;
    float* wp = wsp + ((size_t)(n * 16 + g) * 8 + e) * 2;
    wp[0] = S1; wp[1] = S2;
  }
}

// ---------- epilogue kernel: GN affine + clamp over raw pool extremes ----------
__global__ __launch_bounds__(256) void gn_affine_clamp(
    float* __restrict__ out, const float* __restrict__ wsp,
    const float* __restrict__ gnw, const float* __restrict__ gnb,
    const float* __restrict__ sc, const float* __restrict__ cb) {
  int i = blockIdx.x * 256 + threadIdx.x;
  const int stride = gridDim.x * 256;
  for (; i < TOTAL_OUT; i += stride) {
    int c = (i / 961) & 63;
    int n = i / 61504;
    const float* wp = wsp + ((size_t)(n * 16 + (c >> 2)) * 8) * 2;
    float S1 = 0.f, S2 = 0.f;
#pragma unroll
    for (int e = 0; e < 8; ++e) { S1 += wp[2 * e]; S2 += wp[2 * e + 1]; }
    constexpr float invN = 1.f / (4.f * MPX);
    float mean = S1 * invN;
    float var = S2 * invN - mean * mean;
    float inv = rsqrtf(var + EPS);
    float gw = gnw[c];
    float A = gw * inv * sc[c];
    float B = (gnb[c] - mean * inv * gw) * sc[c] + A * cb[c];
    float v = fmaf(A, out[i], B);
    out[i] = fminf(fmaxf(v, 0.f), 1.f);
  }
}

// ---------- f32 fallback (verbatim R6 winner, used only if ws too small) ----------
#define FIN(T, DOSTATS, RE)                                                    \
  {                                                                            \
    float f0 = T[0] + __shfl_xor(T[0], 32, 64);                                \
    float f1 = T[1] + __shfl_xor(T[1], 32, 64);                                \
    float f2 = T[2] + __shfl_xor(T[2], 32, 64);                                \
    float f3 = T[3] + __shfl_xor(T[3], 32, 64);                                \
    if (DOSTATS) {                                                             \
      s1 += f0 + f1 + m23 * (f2 + f3);                                         \
      float qa = fmaf(f0, f0, f1 * f1);                                        \
      float qb = fmaf(f2, f2, f3 * f3);                                        \
      s2 += qa + m23 * qb;                                                     \
    }                                                                          \
    RE = fmaxf(fmaxf(flip * f0, flip * f1), fmaxf(flip * f2, flip * f3));      \
  }
#define ZERO(T) { T[0] = 0.f; T[1] = 0.f; T[2] = 0.f; T[3] = 0.f; }
#define ROWF(RR, T2, T1, T0)                                                   \
  {                                                                            \
    _Pragma("unroll") for (int i4 = 0; i4 < 4; ++i4) {                         \
      const float* rp = bp + (4 * p + i4) * ICS + (RR) * IW + 4 * j;           \
      float4 v4 = *reinterpret_cast<const float4*>(rp);                        \
      float2 v2 = *reinterpret_cast<const float2*>(rp + 4);                    \
      float in[6] = {v4.x, v4.y, v4.z, v4.w, v2.x, v2.y};                      \
      _Pragma("unroll") for (int dw = 0; dw < 3; ++dw) {                       \
        const float w0 = wf[i4 * 9 + dw];                                      \
        const float w1 = wf[i4 * 9 + 3 + dw];                                  \
        const float w2 = wf[i4 * 9 + 6 + dw];                                  \
        _Pragma("unroll") for (int q = 0; q < 4; ++q) {                        \
          T2[q] = fmaf(in[q + dw], w2, T2[q]);                                 \
          T1[q] = fmaf(in[q + dw], w1, T1[q]);                                 \
          T0[q] = fmaf(in[q + dw], w0, T0[q]);                                 \
        }                                                                      \
      }                                                                        \
    }                                                                          \
  }
#define STAGEF(S, X, Y, Z, DOS01, DOWIN)                                       \
  {                                                                            \
    __syncthreads();                                                           \
    const int cur = (S) & 1;                                                   \
    if ((S) < 31) issue(4 * ((S) + 1), cur ^ 1);                               \
    const float* bp = &buf[cur][0][0];                                         \
    float re0, re1, re2, re3;                                                  \
    ROWF(0, X, Y, Z) FIN(X, DOS01, re0) ZERO(X)                                \
    ROWF(1, Y, Z, X) FIN(Y, DOS01, re1) ZERO(Y)                                \
    if (DOWIN) {                                                               \
      float wfin = fmaxf(wprev, fmaxf(re0, re1));                              \
      if (p == 0 && j < 31) mm[c][(S) - 1][j] = __float2half(flip * wfin);     \
    }                                                                          \
    ROWF(2, Z, X, Y) FIN(Z, true, re2) ZERO(Z)                                 \
    ROWF(3, X, Y, Z) FIN(X, true, re3) ZERO(X)                                 \
    wprev = fmaxf(re2, re3);                                                   \
  }

__global__ __launch_bounds__(256, 2) void fused_conv_gn_pool_f32(
    const float* __restrict__ x, const float* __restrict__ cw,
    const float* __restrict__ cb, const float* __restrict__ gnw,
    const float* __restrict__ gnb, const float* __restrict__ sc,
    float* __restrict__ out) {
  __shared__ float buf[2][ICH][ICS];
  __shared__ __half mm[CPG][PH][PH];
  __shared__ float red[8];
  __shared__ float stats[2];

  const int bid = blockIdx.x;
  const int xcd = bid & 7;
  const int kb = bid >> 3;
  const int n = xcd * 16 + (kb >> 4);
  const int g = kb & 15;
  const int t = threadIdx.x;
  const int c = t >> 6;
  const int u = t & 63;
  const int p = u >> 5;
  const int j = u & 31;
  const int gc = g * CPG + c;

  float wf[36];
  {
    const float4* wp = reinterpret_cast<const float4*>(cw + gc * 72 + p * 36);
#pragma unroll
    for (int q = 0; q < 9; ++q) {
      float4 v = wp[q];
      wf[4 * q + 0] = v.x; wf[4 * q + 1] = v.y;
      wf[4 * q + 2] = v.z; wf[4 * q + 3] = v.w;
    }
  }
  const float flip = ((gnw[gc] * sc[gc]) >= 0.f) ? 1.f : -1.f;
  const float m23 = (j < 31) ? 1.f : 0.f;

  const float* xn = x + (size_t)n * ICH * IH * IW;

  auto issue = [&](int br, int which) {
#pragma unroll
    for (int k = 0; k < 4; ++k) {
      const int m = c * 4 + k;
      const int ic = m >> 1;
      const int r2 = (m & 1) * 2;
      const float* gp = xn + (size_t)(ic * IH + br + r2) * IW + u * 4;
      gll16(gp, &buf[which][ic][r2 * IW]);
    }
  };

  issue(0, 0);

  float s1 = 0.f, s2 = 0.f, wprev = 0.f;
  float A0[4] = {0, 0, 0, 0}, A1[4] = {0, 0, 0, 0}, A2[4] = {0, 0, 0, 0};

  STAGEF(0, A0, A1, A2, false, false)
  for (int s = 1; s <= 28; s += 3) {
    STAGEF(s,     A1, A2, A0, true, true)
    STAGEF(s + 1, A2, A0, A1, true, true)
    STAGEF(s + 2, A0, A1, A2, true, true)
  }
  STAGEF(31, A1, A2, A0, true, true)

#pragma unroll
  for (int off = 32; off > 0; off >>= 1) {
    s1 += __shfl_down(s1, off, 64);
    s2 += __shfl_down(s2, off, 64);
  }
  const float bc = cb[gc];
  if (u == 0) {
    float t1 = 0.5f * s1, t2 = 0.5f * s2;
    red[c * 2] = t1 + MPX * bc;
    red[c * 2 + 1] = t2 + 2.f * bc * t1 + MPX * bc * bc;
  }
  __syncthreads();
  if (t == 0) {
    float S1 = red[0] + red[2] + red[4] + red[6];
    float S2 = red[1] + red[3] + red[5] + red[7];
    constexpr float invN = 1.f / (CPG * 126.f * 126.f);
    float mean = S1 * invN;
    float var = S2 * invN - mean * mean;
    stats[0] = mean;
    stats[1] = rsqrtf(var + EPS);
  }
  __syncthreads();
  const float mean = stats[0], inv = stats[1];

  float* outp = out + ((size_t)n * 64 + g * CPG) * (PH * PH);
  for (int kk = 0; kk < 16; ++kk) {
    int idx = t + kk * 256;
    if (idx < CPG * PH * PH) {
      int cc = idx / (PH * PH);
      int rem = idx - cc * (PH * PH);
      float e = __half2float(mm[cc][rem / PH][rem % PH]);
      int gcc = g * CPG + cc;
      float gw = gnw[gcc];
      float A = gw * inv * sc[gcc];
      float B = (gnb[gcc] - mean * inv * gw) * sc[gcc] + A * cb[gcc];
      float v = fmaf(A, e, B);
      v = fminf(fmaxf(v, 0.f), 1.f);
      outp[cc * (PH * PH) + rem] = v;
    }
  }
}
}  // namespace

extern "C" void kernel_launch(void* const* d_in, const int* in_sizes, int n_in,
                              void* d_out, int out_size, void* d_ws, size_t ws_size,
                              hipStream_t stream) {
  const float* x   = (const float*)d_in[0];
  const float* cw  = (const float*)d_in[1];
  const float* cb  = (const float*)d_in[2];
  const float* gnw = (const float*)d_in[3];
  const float* gnb = (const float*)d_in[4];
  const float* sc  = (const float*)d_in[5];
  float* out = (float*)d_out;

  if (ws_size >= WS_NEED) {
    u16* xh = (u16*)d_ws;
    float* wsp = (float*)((char*)d_ws + XH_BYTES);
    hipLaunchKernelGGL(pack_f16x8, dim3(8192), dim3(256), 0, stream, x, xh);
    hipLaunchKernelGGL(conv_mfma, dim3(1024), dim3(256), 0, stream,
                       xh, cw, cb, gnw, sc, out, wsp);
    hipLaunchKernelGGL(gn_affine_clamp, dim3(2048), dim3(256), 0, stream,
                       out, wsp, gnw, gnb, sc, cb);
  } else {
    hipLaunchKernelGGL(fused_conv_gn_pool_f32, dim3(2048), dim3(256), 0, stream,
                       x, cw, cb, gnw, gnb, sc, out);
  }
}

// Round 14
// 91.635 us; speedup vs baseline: 3.4495x; 1.0840x over previous
//
#include <hip/hip_runtime.h>
#include <hip/hip_fp16.h>

namespace {
constexpr int ICH = 8, IH = 128, IW = 128;
constexpr int CPG = 4, PH = 31;
constexpr int ICS = 516;
constexpr float EPS = 1e-5f;
constexpr float MPX = 126.f * 126.f;
constexpr int TOTAL_OUT = 128 * 64 * PH * PH;
constexpr size_t WS_NEED = (size_t)128 * 16 * 8 * 2 * 4;   // per-eighth stats

typedef _Float16 v8h __attribute__((ext_vector_type(8)));
typedef float v4f __attribute__((ext_vector_type(4)));
typedef unsigned short u16;
typedef unsigned int u32;

__device__ __forceinline__ void gll16(const void* g, void* l) {
  __builtin_amdgcn_global_load_lds((const __attribute__((address_space(1))) void*)g,
                                   (__attribute__((address_space(3))) void*)l, 16, 0, 0);
}

__device__ __forceinline__ u32 pkh(float a, float b) {
  unsigned short lo = __half_as_ushort(__float2half_rn(a));
  unsigned short hi = __half_as_ushort(__float2half_rn(b));
  return (u32)lo | ((u32)hi << 16);
}

// ---------- main: implicit-GEMM conv via mfma_f32_16x16x32_f16 ----------
// Block = (n, eighth e). 4 waves x 16 oc. K = tap*8+ic (taps 0..8, pad 9..11).
// A: lane holds W[16w + (l&15)][k=(l>>4)*8+i], pre-multiplied by flip(oc);
// B: X[r+dh][c0+(l&15)+dw][ic=i].  C/D: col=l&15, row=(l>>4)*4+q [m89].
// Staging fused (T14): f32 loads -> cvt_pk f16 -> ds_write, no prepass pass.
__global__ __launch_bounds__(256, 2) void conv_mfma(
    const float* __restrict__ x, const float* __restrict__ cw,
    const float* __restrict__ cb, const float* __restrict__ gnw,
    const float* __restrict__ sc, float* __restrict__ out,
    float* __restrict__ wsp) {
  __shared__ __align__(16) u16 ring[12][1056];   // 12 rows x 132 px x 8 ic, 25344 B

  const int bid = blockIdx.x;
  const int n = bid >> 3, e = bid & 7;
  const int out_lo = e * 16;
  const int out_hi = (e == 7) ? 125 : out_lo + 15;
  const int NST = (e == 7) ? 4 : 5;              // e=7 stages rows 112..127 exactly
  const int t = threadIdx.x;
  const int w = t >> 6, l = t & 63;
  const int colB = l & 15, qt = l >> 4;

  // Zero the per-row pixel pad (px 128..131): clamped-tap lanes can read it.
  for (int idx = t; idx < 12 * 32; idx += 256)
    ring[idx >> 5][1024 + (idx & 31)] = 0;

  // A fragments (weights), zero-padded taps 9..11, flip folded in (sign of
  // gnw*sc for this A-row's oc): pool-max then needs NO per-element multiply.
  const int ocA = 16 * w + colB;
  const float flipA = (gnw[ocA] * sc[ocA] >= 0.f) ? 1.f : -1.f;
  v8h af[3];
#pragma unroll
  for (int kc = 0; kc < 3; ++kc) {
    const int tap = kc * 4 + qt;
#pragma unroll
    for (int i = 0; i < 8; ++i)
      af[kc][i] = (tap < 9) ? (_Float16)(flipA * cw[ocA * 72 + i * 9 + tap])
                            : (_Float16)0.f;
  }
  // B per-lane address constants (tap clamped to 8 for pad lanes: A=0 there).
  int eofc[3], dhl[3];
#pragma unroll
  for (int kc = 0; kc < 3; ++kc) {
    int tap = kc * 4 + qt; tap = (tap > 8) ? 8 : tap;
    dhl[kc] = tap / 3;
    eofc[kc] = (colB + tap % 3) * 8;
  }
  float flip[4];
#pragma unroll
  for (int q = 0; q < 4; ++q) {
    int oc = 16 * w + qt * 4 + q;
    flip[q] = (gnw[oc] * sc[oc] >= 0.f) ? 1.f : -1.f;
  }
  const u16* rb = &ring[0][0];

  // ---- fused staging: thread t handles pixel (t&127) of rows 2*(t>>7)+{0,1} ----
  const int prg = t >> 7;                  // row-pair group 0..1
  const int px = t & 127;
  const float* xb = x + ((size_t)n * ICH) * (IH * IW) + px;
  float fs[16];                            // [rowInPair][ic], static-indexed
  auto load_regs = [&](int s) {
#pragma unroll
    for (int rr = 0; rr < 2; ++rr) {
      const int grow = out_lo + 4 * s + 2 * prg + rr;
      const float* gp = xb + (size_t)grow * IW;
#pragma unroll
      for (int ic = 0; ic < 8; ++ic)
        fs[rr * 8 + ic] = gp[(size_t)ic * (IH * IW)];
    }
  };
  auto write_lds = [&](int s) {
#pragma unroll
    for (int rr = 0; rr < 2; ++rr) {
      const int grow = out_lo + 4 * s + 2 * prg + rr;
      const int slot = grow % 12;
      uint4 v;
      v.x = pkh(fs[rr * 8 + 0], fs[rr * 8 + 1]);
      v.y = pkh(fs[rr * 8 + 2], fs[rr * 8 + 3]);
      v.z = pkh(fs[rr * 8 + 4], fs[rr * 8 + 5]);
      v.w = pkh(fs[rr * 8 + 6], fs[rr * 8 + 7]);
      *reinterpret_cast<uint4*>(&ring[slot][px * 8]) = v;
    }
  };

  load_regs(0);
  write_lds(0);

  float s1q[4] = {0.f, 0.f, 0.f, 0.f};
  float s2g = 0.f;
  float pacc[8][4];
#pragma unroll
  for (int ci = 0; ci < 8; ++ci)
#pragma unroll
    for (int q = 0; q < 4; ++q) pacc[ci][q] = -3.4e38f;

  for (int s = 0; s < NST; ++s) {
    __syncthreads();                      // stage s writes visible to all waves
    if (s + 1 < NST) load_regs(s + 1);    // loads fly under the MFMA phase
#pragma unroll
    for (int ri = 0; ri < 4; ++ri) {
      const int r = out_lo + 4 * s - 2 + ri;
      if (r < out_lo || r > out_hi) continue;
      const int rm = r % 12;
      int eoff[3];
#pragma unroll
      for (int kc = 0; kc < 3; ++kc) {
        int sl = rm + dhl[kc];
        if (sl >= 12) sl -= 12;
        eoff[kc] = sl * 1056 + eofc[kc];
      }
#pragma unroll
      for (int ci = 0; ci < 8; ++ci) {
        v4f acc = {0.f, 0.f, 0.f, 0.f};   // holds flip(oc)*conv (no bias)
#pragma unroll
        for (int kc = 0; kc < 3; ++kc) {
          v8h bf = *reinterpret_cast<const v8h*>(rb + eoff[kc] + ci * 128);
          acc = __builtin_amdgcn_mfma_f32_16x16x32_f16(af[kc], bf, acc, 0, 0, 0);
        }
        if (ci < 7) {
#pragma unroll
          for (int q = 0; q < 4; ++q) {
            s1q[q] += acc[q];
            s2g = fmaf(acc[q], acc[q], s2g);
            pacc[ci][q] = fmaxf(pacc[ci][q], acc[q]);
          }
        } else {                           // cols 112..127: mask 126,127 (colB>=14)
          const bool va = (colB < 14);
#pragma unroll
          for (int q = 0; q < 4; ++q) {
            float a = va ? acc[q] : 0.f;
            s1q[q] += a;
            s2g = fmaf(a, a, s2g);
            float fv = va ? acc[q] : -3.4e38f;
            pacc[7][q] = fmaxf(pacc[7][q], fv);
          }
        }
      }
      if ((r & 3) == 3) {                  // flush pool window row pr = r>>2
        const int pr = r >> 2;
        float* ob = out + (((size_t)n * 64 + 16 * w + qt * 4) * PH + pr) * PH;
#pragma unroll
        for (int ci = 0; ci < 8; ++ci) {
#pragma unroll
          for (int q = 0; q < 4; ++q) {
            float pm = pacc[ci][q];
            pm = fmaxf(pm, __shfl_xor(pm, 1, 64));
            pm = fmaxf(pm, __shfl_xor(pm, 2, 64));
            if ((l & 3) == 0 && (ci < 7 || colB < 12)) {  // pc<=30 only
              int pc = ci * 4 + (colB >> 2);
              ob[(size_t)q * (PH * PH) + pc] = flip[q] * pm;   // raw extreme
            }
            pacc[ci][q] = -3.4e38f;
          }
        }
      }
    }
    // ds_write stage s+1 (rows 4s+4..4s+7) -- disjoint from stage-s reads
    // (rows 4s-2..4s+3), so no barrier needed before these writes.
    if (s + 1 < NST) write_lds(s + 1);
  }

  // per-eighth stats reduce (16 lanes); un-flip s1; fold bias with eighth count.
#pragma unroll
  for (int off = 1; off <= 8; off <<= 1) {
#pragma unroll
    for (int q = 0; q < 4; ++q) s1q[q] += __shfl_xor(s1q[q], off, 64);
    s2g += __shfl_xor(s2g, off, 64);
  }
  if ((l & 15) == 0) {
    const float cnte = 126.f * (float)(out_hi - out_lo + 1);   // 16 or 14 rows
    float S1 = 0.f, S2 = s2g;
#pragma unroll
    for (int q = 0; q < 4; ++q) {
      float s1t = flip[q] * s1q[q];        // undo folded flip for the mean
      float b = cb[16 * w + qt * 4 + q];
      S1 += s1t + cnte * b;
      S2 += 2.f * b * s1t + cnte * b * b;
    }
    int g = 4 * w + qt;
    float* wp = wsp + ((size_t)(n * 16 + g) * 8 + e) * 2;
    wp[0] = S1; wp[1] = S2;
  }
}

// ---------- epilogue kernel: GN affine + clamp over raw pool extremes ----------
__global__ __launch_bounds__(256) void gn_affine_clamp(
    float* __restrict__ out, const float* __restrict__ wsp,
    const float* __restrict__ gnw, const float* __restrict__ gnb,
    const float* __restrict__ sc, const float* __restrict__ cb) {
  int i = blockIdx.x * 256 + threadIdx.x;
  const int stride = gridDim.x * 256;
  for (; i < TOTAL_OUT; i += stride) {
    int c = (i / 961) & 63;
    int n = i / 61504;
    const float* wp = wsp + ((size_t)(n * 16 + (c >> 2)) * 8) * 2;
    float S1 = 0.f, S2 = 0.f;
#pragma unroll
    for (int e = 0; e < 8; ++e) { S1 += wp[2 * e]; S2 += wp[2 * e + 1]; }
    constexpr float invN = 1.f / (4.f * MPX);
    float mean = S1 * invN;
    float var = S2 * invN - mean * mean;
    float inv = rsqrtf(var + EPS);
    float gw = gnw[c];
    float A = gw * inv * sc[c];
    float B = (gnb[c] - mean * inv * gw) * sc[c] + A * cb[c];
    float v = fmaf(A, out[i], B);
    out[i] = fminf(fmaxf(v, 0.f), 1.f);
  }
}

// ---------- f32 fallback (verbatim R6 winner, used only if ws too small) ----------
#define FIN(T, DOSTATS, RE)                                                    \
  {                                                                            \
    float f0 = T[0] + __shfl_xor(T[0], 32, 64);                                \
    float f1 = T[1] + __shfl_xor(T[1], 32, 64);                                \
    float f2 = T[2] + __shfl_xor(T[2], 32, 64);                                \
    float f3 = T[3] + __shfl_xor(T[3], 32, 64);                                \
    if (DOSTATS) {                                                             \
      s1 += f0 + f1 + m23 * (f2 + f3);                                         \
      float qa = fmaf(f0, f0, f1 * f1);                                        \
      float qb = fmaf(f2, f2, f3 * f3);                                        \
      s2 += qa + m23 * qb;                                                     \
    }                                                                          \
    RE = fmaxf(fmaxf(flip * f0, flip * f1), fmaxf(flip * f2, flip * f3));      \
  }
#define ZERO(T) { T[0] = 0.f; T[1] = 0.f; T[2] = 0.f; T[3] = 0.f; }
#define ROWF(RR, T2, T1, T0)                                                   \
  {                                                                            \
    _Pragma("unroll") for (int i4 = 0; i4 < 4; ++i4) {                         \
      const float* rp = bp + (4 * p + i4) * ICS + (RR) * IW + 4 * j;           \
      float4 v4 = *reinterpret_cast<const float4*>(rp);                        \
      float2 v2 = *reinterpret_cast<const float2*>(rp + 4);                    \
      float in[6] = {v4.x, v4.y, v4.z, v4.w, v2.x, v2.y};                      \
      _Pragma("unroll") for (int dw = 0; dw < 3; ++dw) {                       \
        const float w0 = wf[i4 * 9 + dw];                                      \
        const float w1 = wf[i4 * 9 + 3 + dw];                                  \
        const float w2 = wf[i4 * 9 + 6 + dw];                                  \
        _Pragma("unroll") for (int q = 0; q < 4; ++q) {                        \
          T2[q] = fmaf(in[q + dw], w2, T2[q]);                                 \
          T1[q] = fmaf(in[q + dw], w1, T1[q]);                                 \
          T0[q] = fmaf(in[q + dw], w0, T0[q]);                                 \
        }                                                                      \
      }                                                                        \
    }                                                                          \
  }
#define STAGEF(S, X, Y, Z, DOS01, DOWIN)                                       \
  {                                                                            \
    __syncthreads();                                                           \
    const int cur = (S) & 1;                                                   \
    if ((S) < 31) issue(4 * ((S) + 1), cur ^ 1);                               \
    const float* bp = &buf[cur][0][0];                                         \
    float re0, re1, re2, re3;                                                  \
    ROWF(0, X, Y, Z) FIN(X, DOS01, re0) ZERO(X)                                \
    ROWF(1, Y, Z, X) FIN(Y, DOS01, re1) ZERO(Y)                                \
    if (DOWIN) {                                                               \
      float wfin = fmaxf(wprev, fmaxf(re0, re1));                              \
      if (p == 0 && j < 31) mm[c][(S) - 1][j] = __float2half(flip * wfin);     \
    }                                                                          \
    ROWF(2, Z, X, Y) FIN(Z, true, re2) ZERO(Z)                                 \
    ROWF(3, X, Y, Z) FIN(X, true, re3) ZERO(X)                                 \
    wprev = fmaxf(re2, re3);                                                   \
  }

__global__ __launch_bounds__(256, 2) void fused_conv_gn_pool_f32(
    const float* __restrict__ x, const float* __restrict__ cw,
    const float* __restrict__ cb, const float* __restrict__ gnw,
    const float* __restrict__ gnb, const float* __restrict__ sc,
    float* __restrict__ out) {
  __shared__ float buf[2][ICH][ICS];
  __shared__ __half mm[CPG][PH][PH];
  __shared__ float red[8];
  __shared__ float stats[2];

  const int bid = blockIdx.x;
  const int xcd = bid & 7;
  const int kb = bid >> 3;
  const int n = xcd * 16 + (kb >> 4);
  const int g = kb & 15;
  const int t = threadIdx.x;
  const int c = t >> 6;
  const int u = t & 63;
  const int p = u >> 5;
  const int j = u & 31;
  const int gc = g * CPG + c;

  float wf[36];
  {
    const float4* wp = reinterpret_cast<const float4*>(cw + gc * 72 + p * 36);
#pragma unroll
    for (int q = 0; q < 9; ++q) {
      float4 v = wp[q];
      wf[4 * q + 0] = v.x; wf[4 * q + 1] = v.y;
      wf[4 * q + 2] = v.z; wf[4 * q + 3] = v.w;
    }
  }
  const float flip = ((gnw[gc] * sc[gc]) >= 0.f) ? 1.f : -1.f;
  const float m23 = (j < 31) ? 1.f : 0.f;

  const float* xn = x + (size_t)n * ICH * IH * IW;

  auto issue = [&](int br, int which) {
#pragma unroll
    for (int k = 0; k < 4; ++k) {
      const int m = c * 4 + k;
      const int ic = m >> 1;
      const int r2 = (m & 1) * 2;
      const float* gp = xn + (size_t)(ic * IH + br + r2) * IW + u * 4;
      gll16(gp, &buf[which][ic][r2 * IW]);
    }
  };

  issue(0, 0);

  float s1 = 0.f, s2 = 0.f, wprev = 0.f;
  float A0[4] = {0, 0, 0, 0}, A1[4] = {0, 0, 0, 0}, A2[4] = {0, 0, 0, 0};

  STAGEF(0, A0, A1, A2, false, false)
  for (int s = 1; s <= 28; s += 3) {
    STAGEF(s,     A1, A2, A0, true, true)
    STAGEF(s + 1, A2, A0, A1, true, true)
    STAGEF(s + 2, A0, A1, A2, true, true)
  }
  STAGEF(31, A1, A2, A0, true, true)

#pragma unroll
  for (int off = 32; off > 0; off >>= 1) {
    s1 += __shfl_down(s1, off, 64);
    s2 += __shfl_down(s2, off, 64);
  }
  const float bc = cb[gc];
  if (u == 0) {
    float t1 = 0.5f * s1, t2 = 0.5f * s2;
    red[c * 2] = t1 + MPX * bc;
    red[c * 2 + 1] = t2 + 2.f * bc * t1 + MPX * bc * bc;
  }
  __syncthreads();
  if (t == 0) {
    float S1 = red[0] + red[2] + red[4] + red[6];
    float S2 = red[1] + red[3] + red[5] + red[7];
    constexpr float invN = 1.f / (CPG * 126.f * 126.f);
    float mean = S1 * invN;
    float var = S2 * invN - mean * mean;
    stats[0] = mean;
    stats[1] = rsqrtf(var + EPS);
  }
  __syncthreads();
  const float mean = stats[0], inv = stats[1];

  float* outp = out + ((size_t)n * 64 + g * CPG) * (PH * PH);
  for (int kk = 0; kk < 16; ++kk) {
    int idx = t + kk * 256;
    if (idx < CPG * PH * PH) {
      int cc = idx / (PH * PH);
      int rem = idx - cc * (PH * PH);
      float e = __half2float(mm[cc][rem / PH][rem % PH]);
      int gcc = g * CPG + cc;
      float gw = gnw[gcc];
      float A = gw * inv * sc[gcc];
      float B = (gnb[gcc] - mean * inv * gw) * sc[gcc] + A * cb[gcc];
      float v = fmaf(A, e, B);
      v = fminf(fmaxf(v, 0.f), 1.f);
      outp[cc * (PH * PH) + rem] = v;
    }
  }
}
}  // namespace

extern "C" void kernel_launch(void* const* d_in, const int* in_sizes, int n_in,
                              void* d_out, int out_size, void* d_ws, size_t ws_size,
                              hipStream_t stream) {
  const float* x   = (const float*)d_in[0];
  const float* cw  = (const float*)d_in[1];
  const float* cb  = (const float*)d_in[2];
  const float* gnw = (const float*)d_in[3];
  const float* gnb = (const float*)d_in[4];
  const float* sc  = (const float*)d_in[5];
  float* out = (float*)d_out;

  if (ws_size >= WS_NEED) {
    float* wsp = (float*)d_ws;
    hipLaunchKernelGGL(conv_mfma, dim3(1024), dim3(256), 0, stream,
                       x, cw, cb, gnw, sc, out, wsp);
    hipLaunchKernelGGL(gn_affine_clamp, dim3(2048), dim3(256), 0, stream,
                       out, wsp, gnw, gnb, sc, cb);
  } else {
    hipLaunchKernelGGL(fused_conv_gn_pool_f32, dim3(2048), dim3(256), 0, stream,
                       x, cw, cb, gnw, gnb, sc, out);
  }
}